// Round 12
// baseline (181.350 us; speedup 1.0000x reference)
//
#include <hip/hip_runtime.h>

#define N_NODES 200000
#define N_EDGES 6400000
#define IN_DIM 15
#define POS_DIM 4

#define CSHIFT 9
#define CMASK 511
#define NCOARSE ((N_NODES + 511) >> 9)              // 391 buckets of 512 nodes
#define CHUNK 12288                                 // edges per scatter block
#define NBLK ((N_EDGES + CHUNK - 1) / CHUNK)        // 521 (~2.03 blocks/CU, clean 2 rounds)
#define CAP 17408                                   // per-bucket capacity (mean 16384 + 8 sigma)
#define HCAP 8704                                   // per-half-bucket capacity (mean 8192 + 8 sigma)

typedef unsigned uv4 __attribute__((ext_vector_type(4)));
typedef int      iv4 __attribute__((ext_vector_type(4)));   // nontemporal needs ext_vector, not HIP int4

// MEASURED (r3/r4): divergent ds_add_f32 ~4.3 cy/lane, pipes idle -> never
// stream f32 LDS atomics; u32 LDS atomics are fast.
// MEASURED (r5/r7/r10): agg thread budget = threads-per-node x nodes; 2
// threads/node doubled occupancy 27->45% and cut agg 48.5->41.6us; remaining
// loss is grid quantization (391 blocks, 2/CU cap -> 30% makespan waste) and
// short gather runs. r11: half-bucket blocks (grid 782, 4 blk/CU) + 1024-thr
// scatter at CHUNK 12288 (grid 521, 2 clean rounds, 32 waves/CU).
// MEASURED (r8): <=10-entry copy-out runs -> write amplification. 31-entry ok.
// r11 bench: container died pre-verdict (3rd occurrence; r6->r7 proved this
// mode is infra flake). Audit clean -> resubmitted unchanged.

// ---------------- Pass A: per-node j-side table (+ gcnt zero) ----------------
__global__ void node_prep(const float* __restrict__ x,
                          const float* __restrict__ Wlin,
                          const float* __restrict__ Wsrc,
                          const float* __restrict__ Wpos,
                          float4* __restrict__ tabJ,
                          unsigned* __restrict__ gcnt)
{
    int n = blockIdx.x * blockDim.x + threadIdx.x;
    if (n < NCOARSE) gcnt[n] = 0u;                  // zero bucket counters inline
    if (n >= N_NODES) return;
    const float* xp = x + (long)n * IN_DIM;
    float xv[IN_DIM];
#pragma unroll
    for (int k = 0; k < IN_DIM; ++k) xv[k] = xp[k];

    float p0 = 0.f, p1 = 0.f;
#pragma unroll
    for (int k = 0; k < POS_DIM; ++k) {
        p0 += Wpos[k] * xv[k];
        p1 += Wpos[POS_DIM + k] * xv[k];
    }
    float v0 = 0.f, v1 = 0.f, as0 = 0.f, as1 = 0.f;
#pragma unroll
    for (int k = 0; k < IN_DIM; ++k) {
        float xk = xv[k];
        v0  += Wlin[k] * xk;  v1  += Wlin[IN_DIM + k] * xk;
        as0 += Wsrc[k] * xk;  as1 += Wsrc[IN_DIM + k] * xk;
    }
    tabJ[n] = make_float4(as0 + p0, as1 + p1, v0 - p0, v1 - p1);
}

// ---------------- K1: LDS-staged scatter, 512-node buckets, 1024 threads ----
__global__ __launch_bounds__(1024) void
scatter_kernel(const int* __restrict__ idx,
               unsigned* __restrict__ gcnt,
               unsigned* __restrict__ packed)
{
    __shared__ unsigned stage[CHUNK];        // 48 KB
    __shared__ unsigned cnt[512];            // hist -> cur
    __shared__ unsigned lloc[512];           // exclusive local starts
    __shared__ unsigned gdst[NCOARSE];       // this block's offset within bucket
    __shared__ unsigned wsum[8];
    int b = blockIdx.x;
    int t = threadIdx.x;                     // 1024 threads (16 waves)
    int lane = t & 63, wid = t >> 6;
    long s0 = (long)b * CHUNK;
    int end = (int)min((long)CHUNK, (long)N_EDGES - s0);   // always %4==0
    if (t < 512) cnt[t] = 0u;
    __syncthreads();
    // pass 1: local histogram; i values stay in registers for pass 2
    iv4 myi[3];
    {
        int rr = 0;
        for (int e = t * 4; e < end; e += 4096, ++rr) {
            iv4 iv = __builtin_nontemporal_load((const iv4*)(idx + s0 + e));
            myi[rr] = iv;
            atomicAdd(&cnt[iv.x >> CSHIFT], 1u);
            atomicAdd(&cnt[iv.y >> CSHIFT], 1u);
            atomicAdd(&cnt[iv.z >> CSHIFT], 1u);
            atomicAdd(&cnt[iv.w >> CSHIFT], 1u);
        }
    }
    __syncthreads();
    // wave-shuffle inclusive scan over 512 (threads 0..511, 2 barriers)
    unsigned v = 0, s = 0;
    if (t < 512) {
        v = cnt[t];
        s = v;
#pragma unroll
        for (int off = 1; off < 64; off <<= 1) {
            unsigned u = __shfl_up(s, off, 64);
            if (lane >= off) s += u;
        }
        if (lane == 63) wsum[t >> 6] = s;
    }
    __syncthreads();
    if (t < 512) {
        int sw = t >> 6;
        unsigned woff = 0;
#pragma unroll
        for (int w = 0; w < 8; ++w) woff += (w < sw) ? wsum[w] : 0u;
        unsigned ex = woff + s - v;          // exclusive local start
        lloc[t] = ex;
        cnt[t] = ex;                         // cnt becomes cur
        if (t < NCOARSE) gdst[t] = atomicAdd(&gcnt[t], v);  // reserve span
    }
    __syncthreads();
    // pass 2: place into LDS stage, bucket-major (i from registers, read j)
    {
        int rr = 0;
        for (int e = t * 4; e < end; e += 4096, ++rr) {
            iv4 iv = myi[rr];
            iv4 jv = __builtin_nontemporal_load((const iv4*)(idx + N_EDGES + s0 + e));
            unsigned r0 = atomicAdd(&cnt[iv.x >> CSHIFT], 1u);
            unsigned r1 = atomicAdd(&cnt[iv.y >> CSHIFT], 1u);
            unsigned r2 = atomicAdd(&cnt[iv.z >> CSHIFT], 1u);
            unsigned r3 = atomicAdd(&cnt[iv.w >> CSHIFT], 1u);
            stage[r0] = ((unsigned)jv.x << CSHIFT) | ((unsigned)iv.x & CMASK);
            stage[r1] = ((unsigned)jv.y << CSHIFT) | ((unsigned)iv.y & CMASK);
            stage[r2] = ((unsigned)jv.z << CSHIFT) | ((unsigned)iv.z & CMASK);
            stage[r3] = ((unsigned)jv.w << CSHIFT) | ((unsigned)iv.w & CMASK);
        }
    }
    __syncthreads();
    // pass 3: dense copy-out, one wave per bucket run (16 waves, ~31-entry runs)
    for (int bk = wid; bk < NCOARSE; bk += 16) {
        unsigned st  = lloc[bk];
        unsigned len = lloc[bk + 1] - st;            // bk+1 <= 391 < 512; lloc[>=391]=end
        unsigned gb  = gdst[bk];
        unsigned rem = (gb < (unsigned)CAP) ? (unsigned)CAP - gb : 0u;
        if (len > rem) len = rem;                    // loud-fail clamp, never hit
        unsigned* dst = packed + (size_t)bk * CAP + gb;
        for (unsigned e = lane; e < len; e += 64u)
            dst[e] = stage[st + e];
    }
}

// ---------------- K2: half-bucket counting-sort + pair-split register agg ---
// Grid 782 (2 blocks/bucket), 512 threads, 2 threads/node over 256 nodes.
// Each block streams the full bucket region, keeps edges with i-bit8 == half.
// LDS ~38KB -> 4 blocks/CU x 8 waves = 32 waves/CU capacity, 3.05 blocks/CU.
__global__ __launch_bounds__(512) void
bucket_agg_kernel(const unsigned* __restrict__ packed,
                  const unsigned* __restrict__ gcnt,
                  const float* __restrict__ x,
                  const float* __restrict__ Wdst,
                  const float* __restrict__ Wpos,
                  const float4* __restrict__ tabJ,
                  const float* __restrict__ bpos,
                  float2* __restrict__ out)
{
    __shared__ unsigned cache[HCAP + 256];   // node-major j values (+node stagger)
    __shared__ unsigned cnt[256], cur[256];
    __shared__ unsigned wsum[4];
    int blk = blockIdx.x;
    int k = blk >> 1;
    unsigned half = (unsigned)(blk & 1);
    int t = threadIdx.x;                     // 512 threads, pair per node
    int lane = t & 63;
    int r = t >> 1, sub = t & 1;             // r in [0,256)
    float b0 = bpos[0], b1 = bpos[1];
    int gn = (k << CSHIFT) + ((int)half << 8) + r;

    // own-node logits (both partners compute; pair reads broadcast in L1)
    float p0 = 0.f, p1 = 0.f, ad0 = 0.f, ad1 = 0.f;
    if (gn < N_NODES) {
        const float* xp = x + (long)gn * IN_DIM;
        float xv[IN_DIM];
#pragma unroll
        for (int q = 0; q < IN_DIM; ++q) xv[q] = xp[q];
#pragma unroll
        for (int q = 0; q < POS_DIM; ++q) {
            p0 += Wpos[q] * xv[q];
            p1 += Wpos[POS_DIM + q] * xv[q];
        }
#pragma unroll
        for (int q = 0; q < IN_DIM; ++q) {
            ad0 += Wdst[q] * xv[q];
            ad1 += Wdst[IN_DIM + q] * xv[q];
        }
    }
    float a0 = ad0 + p0 + b0, a1 = ad1 + p1 + b1;
    float sn0 = 0.f, sn1 = 0.f, sd0 = 0.f, sd1 = 0.f;

    if (t < 256) cnt[t] = 0u;
    __syncthreads();

    unsigned n = min(gcnt[k], (unsigned)CAP);        // loud-fail clamp, never hit
    const unsigned* pk = packed + (size_t)k * CAP;

#define KEEP(w) ((((w) >> 8) & 1u) == half)
    // pass 1: histogram of matching edges (low 8 bits); cacheable reads so the
    // sibling block and pass 2 hit L2.
    for (unsigned e = 4u * t; e < n; e += 2048u) {
        uv4 p = *(const uv4*)(pk + e);               // aligned 16B in CAP region
        if (KEEP(p.x))               atomicAdd(&cnt[p.x & 255u], 1u);
        if (e + 1 < n && KEEP(p.y))  atomicAdd(&cnt[p.y & 255u], 1u);
        if (e + 2 < n && KEEP(p.z))  atomicAdd(&cnt[p.z & 255u], 1u);
        if (e + 3 < n && KEEP(p.w))  atomicAdd(&cnt[p.w & 255u], 1u);
    }
    __syncthreads();
    // wave-shuffle exclusive scan over 256 (threads 0..255, 4 waves)
    unsigned v = 0, s = 0;
    if (t < 256) {
        v = cnt[t];
        s = v;
#pragma unroll
        for (int off = 1; off < 64; off <<= 1) {
            unsigned u = __shfl_up(s, off, 64);
            if (lane >= off) s += u;
        }
        if (lane == 63) wsum[t >> 6] = s;
    }
    __syncthreads();
    if (t < 256) {
        int sw = t >> 6;
        unsigned woff = 0;
#pragma unroll
        for (int w = 0; w < 4; ++w) woff += (w < sw) ? wsum[w] : 0u;
        cur[t] = woff + s - v + (unsigned)t;         // +node stagger breaks banks
    }
    __syncthreads();
    // pass 2: place bare j into LDS, node-major
    for (unsigned e = 4u * t; e < n; e += 2048u) {
        uv4 p = *(const uv4*)(pk + e);
        if (KEEP(p.x))              { unsigned pos = atomicAdd(&cur[p.x & 255u], 1u); cache[pos] = p.x >> CSHIFT; }
        if (e + 1 < n && KEEP(p.y)) { unsigned pos = atomicAdd(&cur[p.y & 255u], 1u); cache[pos] = p.y >> CSHIFT; }
        if (e + 2 < n && KEEP(p.z)) { unsigned pos = atomicAdd(&cur[p.z & 255u], 1u); cache[pos] = p.z >> CSHIFT; }
        if (e + 3 < n && KEEP(p.w)) { unsigned pos = atomicAdd(&cur[p.w & 255u], 1u); cache[pos] = p.w >> CSHIFT; }
    }
#undef KEEP
    __syncthreads();
    // pass 3: pair-split register aggregation (8-wide unroll)
    unsigned deg   = cnt[r];
    unsigned st    = cur[r] - deg;                   // cur ended at st+deg
    unsigned half0 = (deg + 1) >> 1;
    unsigned myst  = st + (sub ? half0 : 0u);
    unsigned mylen = sub ? (deg - half0) : half0;
    unsigned e = 0;
    for (; e + 8u <= mylen; e += 8u) {
        unsigned j0 = cache[myst + e],     j1 = cache[myst + e + 1];
        unsigned j2 = cache[myst + e + 2], j3 = cache[myst + e + 3];
        unsigned j4 = cache[myst + e + 4], j5 = cache[myst + e + 5];
        unsigned j6 = cache[myst + e + 6], j7 = cache[myst + e + 7];
        float4 f0 = tabJ[j0], f1 = tabJ[j1], f2 = tabJ[j2], f3 = tabJ[j3];
        float4 f4 = tabJ[j4], f5 = tabJ[j5], f6 = tabJ[j6], f7 = tabJ[j7];
        float e00 = __expf(a0 - f0.x), e01 = __expf(a1 - f0.y);
        float e10 = __expf(a0 - f1.x), e11 = __expf(a1 - f1.y);
        float e20 = __expf(a0 - f2.x), e21 = __expf(a1 - f2.y);
        float e30 = __expf(a0 - f3.x), e31 = __expf(a1 - f3.y);
        float e40 = __expf(a0 - f4.x), e41 = __expf(a1 - f4.y);
        float e50 = __expf(a0 - f5.x), e51 = __expf(a1 - f5.y);
        float e60 = __expf(a0 - f6.x), e61 = __expf(a1 - f6.y);
        float e70 = __expf(a0 - f7.x), e71 = __expf(a1 - f7.y);
        sn0 += e00 * f0.z + e10 * f1.z + e20 * f2.z + e30 * f3.z
             + e40 * f4.z + e50 * f5.z + e60 * f6.z + e70 * f7.z;
        sn1 += e01 * f0.w + e11 * f1.w + e21 * f2.w + e31 * f3.w
             + e41 * f4.w + e51 * f5.w + e61 * f6.w + e71 * f7.w;
        sd0 += e00 + e10 + e20 + e30 + e40 + e50 + e60 + e70;
        sd1 += e01 + e11 + e21 + e31 + e41 + e51 + e61 + e71;
    }
    for (; e < mylen; ++e) {
        unsigned j = cache[myst + e];
        float4 fj = tabJ[j];
        float e0 = __expf(a0 - fj.x), e1 = __expf(a1 - fj.y);
        sn0 += e0 * fj.z;  sn1 += e1 * fj.w;
        sd0 += e0;         sd1 += e1;
    }
    // combine partners (lanes 2r, 2r+1 adjacent in the same wave)
    sn0 += __shfl_xor(sn0, 1);  sn1 += __shfl_xor(sn1, 1);
    sd0 += __shfl_xor(sd0, 1);  sd1 += __shfl_xor(sd1, 1);

    if (sub != 0 || gn >= N_NODES) return;
    float o0 = (sn0 + (p0 + b0) * sd0) / (sd0 + 1e-16f);
    float o1 = (sn1 + (p1 + b1) * sd1) / (sd1 + 1e-16f);
    out[gn] = make_float2(o0, o1);
}

extern "C" void kernel_launch(void* const* d_in, const int* in_sizes, int n_in,
                              void* d_out, int out_size, void* d_ws, size_t ws_size,
                              hipStream_t stream) {
    const float* x    = (const float*)d_in[0];
    const int*   idx  = (const int*)d_in[1];   // (2, E) flat: [0..E)=i, [E..2E)=j
    const float* Wlin = (const float*)d_in[2];
    const float* Wsrc = (const float*)d_in[3];
    const float* Wdst = (const float*)d_in[4];
    const float* Wpos = (const float*)d_in[5];
    const float* bpos = (const float*)d_in[6];
    float* out = (float*)d_out;

    char* ws = (char*)d_ws;
    size_t off = 0;
    float4* tabJ = (float4*)(ws + off); off += (size_t)N_NODES * 16;             //  3.2 MB
    unsigned* packed = (unsigned*)(ws + off); off += (size_t)NCOARSE * CAP * 4;  // 27.2 MB
    unsigned* gcnt   = (unsigned*)(ws + off); off += (size_t)NCOARSE * 4;        // ~30.4 MB total (proven)

    node_prep<<<(N_NODES + 255) / 256, 256, 0, stream>>>(x, Wlin, Wsrc, Wpos,
                                                         tabJ, gcnt);
    scatter_kernel<<<NBLK, 1024, 0, stream>>>(idx, gcnt, packed);
    bucket_agg_kernel<<<NCOARSE * 2, 512, 0, stream>>>(packed, gcnt,
                                                       x, Wdst, Wpos, tabJ, bpos,
                                                       (float2*)out);
}

// Round 13
// 164.809 us; speedup vs baseline: 1.1004x; 1.1004x over previous
//
#include <hip/hip_runtime.h>

#define N_NODES 200000
#define N_EDGES 6400000
#define IN_DIM 15
#define POS_DIM 4

#define CSHIFT 9
#define CMASK 511
#define NCOARSE ((N_NODES + 511) >> 9)              // 391 buckets of 512 nodes
#define CHUNK 12288                                 // edges per scatter block
#define NBLK ((N_EDGES + CHUNK - 1) / CHUNK)        // 521 (last block end=10240, %2048==0)
#define CAP 17408                                   // per-bucket capacity (mean 16384 + 8 sigma)

typedef unsigned uv4 __attribute__((ext_vector_type(4)));
typedef int      iv4 __attribute__((ext_vector_type(4)));

// MEASURED (r3/r4): divergent ds_add_f32 ~1 cy/LANE-op serialized, pipes idle
// -> never stream f32 LDS atomics; u32 LDS atomics are wave-parallel & fast.
// MEASURED (r5/r7/r10): agg wave budget = threads/node x nodes; 2 thr/node
// (r10: 1024thr, full 512-node bucket) = 41.6us, occ 45%, FETCH 31.6MB.
// MODEL (r12 close): agg pass-3 = 25.6M random 16B gathers -> 64B L2 lines
// -> ~1.6GB L2 traffic -> 42-46us at L2 ceiling = measured 41.6. Agg is AT
// its L2-line roofline; j-locality fix incompatible with i-grouped regs.
// MEASURED (r12): half-bucket agg split doubles FETCH (68.4MB) - siblings
// don't share L2. Dead in both variants (r7, r12).
// MEASURED (r8): <=10-entry copy-out runs -> write amplification (67MB).
// 31-entry runs OK. Scatter r13: CHUNK 12288/512thr, LDS slim 51.6KB (drop
// lloc; cnt-as-cur doubles as run-end table) -> 3 blk/CU, grid 521 = 2.03/CU.

// ---------------- Pass A: per-node j-side table (+ gcnt zero) ----------------
__global__ void node_prep(const float* __restrict__ x,
                          const float* __restrict__ Wlin,
                          const float* __restrict__ Wsrc,
                          const float* __restrict__ Wpos,
                          float4* __restrict__ tabJ,
                          unsigned* __restrict__ gcnt)
{
    int n = blockIdx.x * blockDim.x + threadIdx.x;
    if (n < NCOARSE) gcnt[n] = 0u;                  // zero bucket counters inline
    if (n >= N_NODES) return;
    const float* xp = x + (long)n * IN_DIM;
    float xv[IN_DIM];
#pragma unroll
    for (int k = 0; k < IN_DIM; ++k) xv[k] = xp[k];

    float p0 = 0.f, p1 = 0.f;
#pragma unroll
    for (int k = 0; k < POS_DIM; ++k) {
        p0 += Wpos[k] * xv[k];
        p1 += Wpos[POS_DIM + k] * xv[k];
    }
    float v0 = 0.f, v1 = 0.f, as0 = 0.f, as1 = 0.f;
#pragma unroll
    for (int k = 0; k < IN_DIM; ++k) {
        float xk = xv[k];
        v0  += Wlin[k] * xk;  v1  += Wlin[IN_DIM + k] * xk;
        as0 += Wsrc[k] * xk;  as1 += Wsrc[IN_DIM + k] * xk;
    }
    tabJ[n] = make_float4(as0 + p0, as1 + p1, v0 - p0, v1 - p1);
}

// ---------------- K1: LDS-staged scatter, 512-node buckets, slim LDS --------
// 512 threads, CHUNK 12288, grid 521. LDS 51.6KB -> 3 blocks/CU (24 waves/CU
// capacity, 2.03 blocks/CU supplied -> clean 2-round makespan vs r5's 391@2).
__global__ __launch_bounds__(512) void
scatter_kernel(const int* __restrict__ idx,
               unsigned* __restrict__ gcnt,
               unsigned* __restrict__ packed)
{
    __shared__ unsigned stage[CHUNK];        // 48 KB
    __shared__ unsigned cnt[512];            // hist -> cur -> run-end table
    __shared__ unsigned gdst[NCOARSE];       // this block's offset within bucket
    __shared__ unsigned wsum[8];
    int b = blockIdx.x;
    int t = threadIdx.x;                     // 512 threads (8 waves)
    int lane = t & 63, wid = t >> 6;
    long s0 = (long)b * CHUNK;
    int end = (int)min((long)CHUNK, (long)N_EDGES - s0);   // %2048==0
    cnt[t] = 0u;
    __syncthreads();
    // pass 1: local histogram; i values stay in registers for pass 2
    iv4 myi[6];
    {
        int rr = 0;
        for (int e = t * 4; e < end; e += 2048, ++rr) {
            iv4 iv = *(const iv4*)(idx + s0 + e);
            myi[rr] = iv;
            atomicAdd(&cnt[iv.x >> CSHIFT], 1u);
            atomicAdd(&cnt[iv.y >> CSHIFT], 1u);
            atomicAdd(&cnt[iv.z >> CSHIFT], 1u);
            atomicAdd(&cnt[iv.w >> CSHIFT], 1u);
        }
    }
    __syncthreads();
    // wave-shuffle inclusive scan over 512 (2 barriers)
    unsigned v = cnt[t];
    unsigned s = v;
#pragma unroll
    for (int off = 1; off < 64; off <<= 1) {
        unsigned u = __shfl_up(s, off, 64);
        if (lane >= off) s += u;
    }
    if (lane == 63) wsum[wid] = s;
    __syncthreads();
    unsigned woff = 0;
#pragma unroll
    for (int w = 0; w < 8; ++w) woff += (w < wid) ? wsum[w] : 0u;
    {
        unsigned ex = woff + s - v;          // exclusive local start
        cnt[t] = ex;                         // cnt becomes cur
        if (t < NCOARSE) gdst[t] = atomicAdd(&gcnt[t], v);  // reserve span
    }
    __syncthreads();
    // pass 2: place into LDS stage, bucket-major (i from registers, read j)
    {
        int rr = 0;
        for (int e = t * 4; e < end; e += 2048, ++rr) {
            iv4 iv = myi[rr];
            iv4 jv = *(const iv4*)(idx + N_EDGES + s0 + e);
            unsigned r0 = atomicAdd(&cnt[iv.x >> CSHIFT], 1u);
            unsigned r1 = atomicAdd(&cnt[iv.y >> CSHIFT], 1u);
            unsigned r2 = atomicAdd(&cnt[iv.z >> CSHIFT], 1u);
            unsigned r3 = atomicAdd(&cnt[iv.w >> CSHIFT], 1u);
            stage[r0] = ((unsigned)jv.x << CSHIFT) | ((unsigned)iv.x & CMASK);
            stage[r1] = ((unsigned)jv.y << CSHIFT) | ((unsigned)iv.y & CMASK);
            stage[r2] = ((unsigned)jv.z << CSHIFT) | ((unsigned)iv.z & CMASK);
            stage[r3] = ((unsigned)jv.w << CSHIFT) | ((unsigned)iv.w & CMASK);
        }
    }
    __syncthreads();
    // pass 3: dense copy-out; run bounds reconstructed from cnt (cur==run end)
    for (int bk = wid; bk < NCOARSE; bk += 8) {
        unsigned st  = bk ? cnt[bk - 1] : 0u;
        unsigned len = cnt[bk] - st;                 // ~31-entry runs
        unsigned gb  = gdst[bk];
        unsigned rem = (gb < (unsigned)CAP) ? (unsigned)CAP - gb : 0u;
        if (len > rem) len = rem;                    // loud-fail clamp, never hit
        unsigned* dst = packed + (size_t)bk * CAP + gb;
        for (unsigned e = lane; e < len; e += 64u)
            dst[e] = stage[st + e];
    }
}

// ---------------- K2: counting-sort + register agg, 2 threads/node ----------
// r10-verbatim (measured 41.6us = its L2-line gather roofline). 1024 threads,
// full 512-node bucket, pair (2r,2r+1) splits node r's run, shfl_xor combine.
__global__ __launch_bounds__(1024) void
bucket_agg_kernel(const unsigned* __restrict__ packed,
                  const unsigned* __restrict__ gcnt,
                  const float* __restrict__ x,
                  const float* __restrict__ Wdst,
                  const float* __restrict__ Wpos,
                  const float4* __restrict__ tabJ,
                  const float* __restrict__ bpos,
                  float2* __restrict__ out)
{
    __shared__ unsigned cache[CAP + 512];    // node-major j values (+node stagger)
    __shared__ unsigned cnt[512], cur[512];
    __shared__ unsigned wsum[8];
    int k = blockIdx.x;
    int t = threadIdx.x;                     // 1024 threads, pair per node
    int lane = t & 63;
    int r = t >> 1, sub = t & 1;
    float b0 = bpos[0], b1 = bpos[1];
    int gn = (k << CSHIFT) + r;

    // own-node logits (both partners compute; pair reads broadcast in L1)
    float p0 = 0.f, p1 = 0.f, ad0 = 0.f, ad1 = 0.f;
    if (gn < N_NODES) {
        const float* xp = x + (long)gn * IN_DIM;
        float xv[IN_DIM];
#pragma unroll
        for (int q = 0; q < IN_DIM; ++q) xv[q] = xp[q];
#pragma unroll
        for (int q = 0; q < POS_DIM; ++q) {
            p0 += Wpos[q] * xv[q];
            p1 += Wpos[POS_DIM + q] * xv[q];
        }
#pragma unroll
        for (int q = 0; q < IN_DIM; ++q) {
            ad0 += Wdst[q] * xv[q];
            ad1 += Wdst[IN_DIM + q] * xv[q];
        }
    }
    float a0 = ad0 + p0 + b0, a1 = ad1 + p1 + b1;
    float sn0 = 0.f, sn1 = 0.f, sd0 = 0.f, sd1 = 0.f;

    if (t < 512) cnt[t] = 0u;
    __syncthreads();

    unsigned n = min(gcnt[k], (unsigned)CAP);        // loud-fail clamp, never hit
    const unsigned* pk = packed + (size_t)k * CAP;

    // pass 1: histogram of low 9 bits (all 1024 threads stream)
    for (unsigned e = 4u * t; e < n; e += 4096u) {
        uv4 p = *(const uv4*)(pk + e);               // aligned 16B in CAP region
        atomicAdd(&cnt[p.x & CMASK], 1u);
        if (e + 1 < n) atomicAdd(&cnt[p.y & CMASK], 1u);
        if (e + 2 < n) atomicAdd(&cnt[p.z & CMASK], 1u);
        if (e + 3 < n) atomicAdd(&cnt[p.w & CMASK], 1u);
    }
    __syncthreads();
    // wave-shuffle exclusive scan over 512 (threads 0..511, 8 waves)
    unsigned v = 0, s = 0;
    if (t < 512) {
        v = cnt[t];
        s = v;
#pragma unroll
        for (int off = 1; off < 64; off <<= 1) {
            unsigned u = __shfl_up(s, off, 64);
            if (lane >= off) s += u;
        }
        if (lane == 63) wsum[t >> 6] = s;
    }
    __syncthreads();
    if (t < 512) {
        int wid = t >> 6;
        unsigned woff = 0;
#pragma unroll
        for (int w = 0; w < 8; ++w) woff += (w < wid) ? wsum[w] : 0u;
        cur[t] = woff + s - v + (unsigned)t;         // +node stagger breaks banks
    }
    __syncthreads();
    // pass 2: place bare j into LDS, node-major (region L2-hot from pass 1)
    for (unsigned e = 4u * t; e < n; e += 4096u) {
        uv4 p = __builtin_nontemporal_load((const uv4*)(pk + e));
        { unsigned pos = atomicAdd(&cur[p.x & CMASK], 1u); cache[pos] = p.x >> CSHIFT; }
        if (e + 1 < n) { unsigned pos = atomicAdd(&cur[p.y & CMASK], 1u); cache[pos] = p.y >> CSHIFT; }
        if (e + 2 < n) { unsigned pos = atomicAdd(&cur[p.z & CMASK], 1u); cache[pos] = p.z >> CSHIFT; }
        if (e + 3 < n) { unsigned pos = atomicAdd(&cur[p.w & CMASK], 1u); cache[pos] = p.w >> CSHIFT; }
    }
    __syncthreads();
    // pass 3: pair-split register aggregation (8-wide unroll)
    unsigned deg   = cnt[r];
    unsigned st    = cur[r] - deg;                   // cur ended at st+deg
    unsigned half0 = (deg + 1) >> 1;
    unsigned myst  = st + (sub ? half0 : 0u);
    unsigned mylen = sub ? (deg - half0) : half0;
    unsigned e = 0;
    for (; e + 8u <= mylen; e += 8u) {
        unsigned j0 = cache[myst + e],     j1 = cache[myst + e + 1];
        unsigned j2 = cache[myst + e + 2], j3 = cache[myst + e + 3];
        unsigned j4 = cache[myst + e + 4], j5 = cache[myst + e + 5];
        unsigned j6 = cache[myst + e + 6], j7 = cache[myst + e + 7];
        float4 f0 = tabJ[j0], f1 = tabJ[j1], f2 = tabJ[j2], f3 = tabJ[j3];
        float4 f4 = tabJ[j4], f5 = tabJ[j5], f6 = tabJ[j6], f7 = tabJ[j7];
        float e00 = __expf(a0 - f0.x), e01 = __expf(a1 - f0.y);
        float e10 = __expf(a0 - f1.x), e11 = __expf(a1 - f1.y);
        float e20 = __expf(a0 - f2.x), e21 = __expf(a1 - f2.y);
        float e30 = __expf(a0 - f3.x), e31 = __expf(a1 - f3.y);
        float e40 = __expf(a0 - f4.x), e41 = __expf(a1 - f4.y);
        float e50 = __expf(a0 - f5.x), e51 = __expf(a1 - f5.y);
        float e60 = __expf(a0 - f6.x), e61 = __expf(a1 - f6.y);
        float e70 = __expf(a0 - f7.x), e71 = __expf(a1 - f7.y);
        sn0 += e00 * f0.z + e10 * f1.z + e20 * f2.z + e30 * f3.z
             + e40 * f4.z + e50 * f5.z + e60 * f6.z + e70 * f7.z;
        sn1 += e01 * f0.w + e11 * f1.w + e21 * f2.w + e31 * f3.w
             + e41 * f4.w + e51 * f5.w + e61 * f6.w + e71 * f7.w;
        sd0 += e00 + e10 + e20 + e30 + e40 + e50 + e60 + e70;
        sd1 += e01 + e11 + e21 + e31 + e41 + e51 + e61 + e71;
    }
    for (; e < mylen; ++e) {
        unsigned j = cache[myst + e];
        float4 fj = tabJ[j];
        float e0 = __expf(a0 - fj.x), e1 = __expf(a1 - fj.y);
        sn0 += e0 * fj.z;  sn1 += e1 * fj.w;
        sd0 += e0;         sd1 += e1;
    }
    // combine partners (lanes 2r, 2r+1 adjacent in the same wave)
    sn0 += __shfl_xor(sn0, 1);  sn1 += __shfl_xor(sn1, 1);
    sd0 += __shfl_xor(sd0, 1);  sd1 += __shfl_xor(sd1, 1);

    if (sub != 0 || gn >= N_NODES) return;
    float o0 = (sn0 + (p0 + b0) * sd0) / (sd0 + 1e-16f);
    float o1 = (sn1 + (p1 + b1) * sd1) / (sd1 + 1e-16f);
    out[gn] = make_float2(o0, o1);
}

extern "C" void kernel_launch(void* const* d_in, const int* in_sizes, int n_in,
                              void* d_out, int out_size, void* d_ws, size_t ws_size,
                              hipStream_t stream) {
    const float* x    = (const float*)d_in[0];
    const int*   idx  = (const int*)d_in[1];   // (2, E) flat: [0..E)=i, [E..2E)=j
    const float* Wlin = (const float*)d_in[2];
    const float* Wsrc = (const float*)d_in[3];
    const float* Wdst = (const float*)d_in[4];
    const float* Wpos = (const float*)d_in[5];
    const float* bpos = (const float*)d_in[6];
    float* out = (float*)d_out;

    char* ws = (char*)d_ws;
    size_t off = 0;
    float4* tabJ = (float4*)(ws + off); off += (size_t)N_NODES * 16;             //  3.2 MB
    unsigned* packed = (unsigned*)(ws + off); off += (size_t)NCOARSE * CAP * 4;  // 27.2 MB
    unsigned* gcnt   = (unsigned*)(ws + off); off += (size_t)NCOARSE * 4;        // ~30.4 MB total (proven)

    node_prep<<<(N_NODES + 255) / 256, 256, 0, stream>>>(x, Wlin, Wsrc, Wpos,
                                                         tabJ, gcnt);
    scatter_kernel<<<NBLK, 512, 0, stream>>>(idx, gcnt, packed);
    bucket_agg_kernel<<<NCOARSE, 1024, 0, stream>>>(packed, gcnt,
                                                    x, Wdst, Wpos, tabJ, bpos,
                                                    (float2*)out);
}

// Round 14
// 163.368 us; speedup vs baseline: 1.1101x; 1.0088x over previous
//
#include <hip/hip_runtime.h>

#define N_NODES 200000
#define N_EDGES 6400000
#define IN_DIM 15
#define POS_DIM 4

#define CSHIFT 9
#define CMASK 511
#define NCOARSE ((N_NODES + 511) >> 9)              // 391 buckets of 512 nodes
#define CHUNK 12288                                 // edges per scatter block
#define NBLK ((N_EDGES + CHUNK - 1) / CHUNK)        // 521 (~2.03 blocks/CU)
#define CAP 17408                                   // per-bucket capacity (mean 16384 + 8 sigma)
#define NPB 384                                     // prep nodes per scatter block (521*384 = 200064)

typedef unsigned uv4 __attribute__((ext_vector_type(4)));
typedef int      iv4 __attribute__((ext_vector_type(4)));

// MEASURED (r3/r4): divergent ds_add_f32 serializes per-lane, pipes idle ->
// never stream f32 LDS atomics; u32 LDS atomics are wave-parallel & fast.
// MEASURED (r10/r13): agg (1024thr, 2 thr/node, full bucket) = 42.0us,
// occ 45%, FETCH 31.6MB -- matches the divergent-gather request-throughput
// roofline (25.6M lane-gathers ~= 100K/CU at ~1/cy). Structure closed.
// MEASURED (r12): half-bucket agg split doubles FETCH; siblings don't share
// L2. Dead. MEASURED (r8): <=10-entry copy-out runs -> write amplification.
// MEASURED (r13): fillBufferAligned writes exactly 256MiB -> ws is 256MiB;
// r1/r6/r11 "container failed" were infra flake, not OOM. Workspace is free.
// r14: prep fused into scatter (gcnt via memsetAsync), agg logits from
// precomputed tabI4 (-12MB x re-read), pass-3 copy-out 2 runs/wave.

// ---------------- K1: fused prep + LDS-staged scatter -----------------------
// 512 threads, CHUNK 12288, grid 521. LDS 51.6KB -> 3 blocks/CU.
__global__ __launch_bounds__(512) void
scatter_kernel(const float* __restrict__ x,
               const float* __restrict__ Wlin,
               const float* __restrict__ Wsrc,
               const float* __restrict__ Wdst,
               const float* __restrict__ Wpos,
               const float* __restrict__ bpos,
               const int* __restrict__ idx,
               unsigned* __restrict__ gcnt,
               unsigned* __restrict__ packed,
               float4* __restrict__ tabJ,
               float4* __restrict__ tabI4)
{
    __shared__ unsigned stage[CHUNK];        // 48 KB
    __shared__ unsigned cnt[512];            // hist -> cur -> run-end table
    __shared__ unsigned gdst[NCOARSE];       // this block's offset within bucket
    __shared__ unsigned wsum[8];
    int b = blockIdx.x;
    int t = threadIdx.x;                     // 512 threads (8 waves)
    int lane = t & 63, wid = t >> 6;
    long s0 = (long)b * CHUNK;
    int end = (int)min((long)CHUNK, (long)N_EDGES - s0);   // %2048==0

    // fused node_prep: this block's NPB nodes (runs before/overlapping hist)
    {
        int nb = b * NPB + t;
        if (t < NPB && nb < N_NODES) {
            const float* xp = x + (long)nb * IN_DIM;
            float xv[IN_DIM];
#pragma unroll
            for (int q = 0; q < IN_DIM; ++q) xv[q] = xp[q];
            float p0 = 0.f, p1 = 0.f;
#pragma unroll
            for (int q = 0; q < POS_DIM; ++q) {
                p0 += Wpos[q] * xv[q];
                p1 += Wpos[POS_DIM + q] * xv[q];
            }
            float v0 = 0.f, v1 = 0.f, as0 = 0.f, as1 = 0.f, ad0 = 0.f, ad1 = 0.f;
#pragma unroll
            for (int q = 0; q < IN_DIM; ++q) {
                float xk = xv[q];
                v0  += Wlin[q] * xk;  v1  += Wlin[IN_DIM + q] * xk;
                as0 += Wsrc[q] * xk;  as1 += Wsrc[IN_DIM + q] * xk;
                ad0 += Wdst[q] * xk;  ad1 += Wdst[IN_DIM + q] * xk;
            }
            float b0 = bpos[0], b1 = bpos[1];
            tabJ[nb]  = make_float4(as0 + p0, as1 + p1, v0 - p0, v1 - p1);
            tabI4[nb] = make_float4(ad0 + p0 + b0, ad1 + p1 + b1, p0 + b0, p1 + b1);
        }
    }

    cnt[t] = 0u;
    __syncthreads();
    // pass 1: local histogram; i values stay in registers for pass 2
    iv4 myi[6];
    {
        int rr = 0;
        for (int e = t * 4; e < end; e += 2048, ++rr) {
            iv4 iv = *(const iv4*)(idx + s0 + e);
            myi[rr] = iv;
            atomicAdd(&cnt[iv.x >> CSHIFT], 1u);
            atomicAdd(&cnt[iv.y >> CSHIFT], 1u);
            atomicAdd(&cnt[iv.z >> CSHIFT], 1u);
            atomicAdd(&cnt[iv.w >> CSHIFT], 1u);
        }
    }
    __syncthreads();
    // wave-shuffle inclusive scan over 512 (2 barriers)
    unsigned v = cnt[t];
    unsigned s = v;
#pragma unroll
    for (int off = 1; off < 64; off <<= 1) {
        unsigned u = __shfl_up(s, off, 64);
        if (lane >= off) s += u;
    }
    if (lane == 63) wsum[wid] = s;
    __syncthreads();
    unsigned woff = 0;
#pragma unroll
    for (int w = 0; w < 8; ++w) woff += (w < wid) ? wsum[w] : 0u;
    {
        unsigned ex = woff + s - v;          // exclusive local start
        cnt[t] = ex;                         // cnt becomes cur
        if (t < NCOARSE) gdst[t] = atomicAdd(&gcnt[t], v);  // reserve span
    }
    __syncthreads();
    // pass 2: place into LDS stage, bucket-major (i from registers, read j)
    {
        int rr = 0;
        for (int e = t * 4; e < end; e += 2048, ++rr) {
            iv4 iv = myi[rr];
            iv4 jv = *(const iv4*)(idx + N_EDGES + s0 + e);
            unsigned r0 = atomicAdd(&cnt[iv.x >> CSHIFT], 1u);
            unsigned r1 = atomicAdd(&cnt[iv.y >> CSHIFT], 1u);
            unsigned r2 = atomicAdd(&cnt[iv.z >> CSHIFT], 1u);
            unsigned r3 = atomicAdd(&cnt[iv.w >> CSHIFT], 1u);
            stage[r0] = ((unsigned)jv.x << CSHIFT) | ((unsigned)iv.x & CMASK);
            stage[r1] = ((unsigned)jv.y << CSHIFT) | ((unsigned)iv.y & CMASK);
            stage[r2] = ((unsigned)jv.z << CSHIFT) | ((unsigned)iv.z & CMASK);
            stage[r3] = ((unsigned)jv.w << CSHIFT) | ((unsigned)iv.w & CMASK);
        }
    }
    __syncthreads();
    // pass 3: dense copy-out, TWO runs per wave (runs ~31 entries; 32-lane
    // halves keep lane utilization ~full). Run bounds from cnt (cur==end).
    {
        int h = lane >> 5, lane32 = lane & 31;
        for (int bk = wid * 2 + h; bk < NCOARSE; bk += 16) {
            unsigned st  = bk ? cnt[bk - 1] : 0u;
            unsigned len = cnt[bk] - st;
            unsigned gb  = gdst[bk];
            unsigned rem = (gb < (unsigned)CAP) ? (unsigned)CAP - gb : 0u;
            if (len > rem) len = rem;                // loud-fail clamp, never hit
            unsigned* dst = packed + (size_t)bk * CAP + gb;
            for (unsigned e = lane32; e < len; e += 32u)
                dst[e] = stage[st + e];
        }
    }
}

// ---------------- K2: counting-sort + register agg, 2 threads/node ----------
// r13-verbatim structure (measured 42.0us = divergent-gather roofline);
// logits now read from tabI4 (16B/node) instead of recomputed from x.
__global__ __launch_bounds__(1024) void
bucket_agg_kernel(const unsigned* __restrict__ packed,
                  const unsigned* __restrict__ gcnt,
                  const float4* __restrict__ tabJ,
                  const float4* __restrict__ tabI4,
                  float2* __restrict__ out)
{
    __shared__ unsigned cache[CAP + 512];    // node-major j values (+node stagger)
    __shared__ unsigned cnt[512], cur[512];
    __shared__ unsigned wsum[8];
    int k = blockIdx.x;
    int t = threadIdx.x;                     // 1024 threads, pair per node
    int lane = t & 63;
    int r = t >> 1, sub = t & 1;
    int gn = (k << CSHIFT) + r;

    float4 ai = make_float4(0.f, 0.f, 0.f, 0.f);
    if (gn < N_NODES) ai = tabI4[gn];        // (a0, a1, p0+b0, p1+b1); pair broadcasts
    float a0 = ai.x, a1 = ai.y;
    float sn0 = 0.f, sn1 = 0.f, sd0 = 0.f, sd1 = 0.f;

    if (t < 512) cnt[t] = 0u;
    __syncthreads();

    unsigned n = min(gcnt[k], (unsigned)CAP);        // loud-fail clamp, never hit
    const unsigned* pk = packed + (size_t)k * CAP;

    // pass 1: histogram of low 9 bits (all 1024 threads stream)
    for (unsigned e = 4u * t; e < n; e += 4096u) {
        uv4 p = *(const uv4*)(pk + e);               // aligned 16B in CAP region
        atomicAdd(&cnt[p.x & CMASK], 1u);
        if (e + 1 < n) atomicAdd(&cnt[p.y & CMASK], 1u);
        if (e + 2 < n) atomicAdd(&cnt[p.z & CMASK], 1u);
        if (e + 3 < n) atomicAdd(&cnt[p.w & CMASK], 1u);
    }
    __syncthreads();
    // wave-shuffle exclusive scan over 512 (threads 0..511, 8 waves)
    unsigned v = 0, s = 0;
    if (t < 512) {
        v = cnt[t];
        s = v;
#pragma unroll
        for (int off = 1; off < 64; off <<= 1) {
            unsigned u = __shfl_up(s, off, 64);
            if (lane >= off) s += u;
        }
        if (lane == 63) wsum[t >> 6] = s;
    }
    __syncthreads();
    if (t < 512) {
        int wid = t >> 6;
        unsigned woff = 0;
#pragma unroll
        for (int w = 0; w < 8; ++w) woff += (w < wid) ? wsum[w] : 0u;
        cur[t] = woff + s - v + (unsigned)t;         // +node stagger breaks banks
    }
    __syncthreads();
    // pass 2: place bare j into LDS, node-major (region L2-hot from pass 1)
    for (unsigned e = 4u * t; e < n; e += 4096u) {
        uv4 p = __builtin_nontemporal_load((const uv4*)(pk + e));
        { unsigned pos = atomicAdd(&cur[p.x & CMASK], 1u); cache[pos] = p.x >> CSHIFT; }
        if (e + 1 < n) { unsigned pos = atomicAdd(&cur[p.y & CMASK], 1u); cache[pos] = p.y >> CSHIFT; }
        if (e + 2 < n) { unsigned pos = atomicAdd(&cur[p.z & CMASK], 1u); cache[pos] = p.z >> CSHIFT; }
        if (e + 3 < n) { unsigned pos = atomicAdd(&cur[p.w & CMASK], 1u); cache[pos] = p.w >> CSHIFT; }
    }
    __syncthreads();
    // pass 3: pair-split register aggregation (8-wide unroll)
    unsigned deg   = cnt[r];
    unsigned st    = cur[r] - deg;                   // cur ended at st+deg
    unsigned half0 = (deg + 1) >> 1;
    unsigned myst  = st + (sub ? half0 : 0u);
    unsigned mylen = sub ? (deg - half0) : half0;
    unsigned e = 0;
    for (; e + 8u <= mylen; e += 8u) {
        unsigned j0 = cache[myst + e],     j1 = cache[myst + e + 1];
        unsigned j2 = cache[myst + e + 2], j3 = cache[myst + e + 3];
        unsigned j4 = cache[myst + e + 4], j5 = cache[myst + e + 5];
        unsigned j6 = cache[myst + e + 6], j7 = cache[myst + e + 7];
        float4 f0 = tabJ[j0], f1 = tabJ[j1], f2 = tabJ[j2], f3 = tabJ[j3];
        float4 f4 = tabJ[j4], f5 = tabJ[j5], f6 = tabJ[j6], f7 = tabJ[j7];
        float e00 = __expf(a0 - f0.x), e01 = __expf(a1 - f0.y);
        float e10 = __expf(a0 - f1.x), e11 = __expf(a1 - f1.y);
        float e20 = __expf(a0 - f2.x), e21 = __expf(a1 - f2.y);
        float e30 = __expf(a0 - f3.x), e31 = __expf(a1 - f3.y);
        float e40 = __expf(a0 - f4.x), e41 = __expf(a1 - f4.y);
        float e50 = __expf(a0 - f5.x), e51 = __expf(a1 - f5.y);
        float e60 = __expf(a0 - f6.x), e61 = __expf(a1 - f6.y);
        float e70 = __expf(a0 - f7.x), e71 = __expf(a1 - f7.y);
        sn0 += e00 * f0.z + e10 * f1.z + e20 * f2.z + e30 * f3.z
             + e40 * f4.z + e50 * f5.z + e60 * f6.z + e70 * f7.z;
        sn1 += e01 * f0.w + e11 * f1.w + e21 * f2.w + e31 * f3.w
             + e41 * f4.w + e51 * f5.w + e61 * f6.w + e71 * f7.w;
        sd0 += e00 + e10 + e20 + e30 + e40 + e50 + e60 + e70;
        sd1 += e01 + e11 + e21 + e31 + e41 + e51 + e61 + e71;
    }
    for (; e < mylen; ++e) {
        unsigned j = cache[myst + e];
        float4 fj = tabJ[j];
        float e0 = __expf(a0 - fj.x), e1 = __expf(a1 - fj.y);
        sn0 += e0 * fj.z;  sn1 += e1 * fj.w;
        sd0 += e0;         sd1 += e1;
    }
    // combine partners (lanes 2r, 2r+1 adjacent in the same wave)
    sn0 += __shfl_xor(sn0, 1);  sn1 += __shfl_xor(sn1, 1);
    sd0 += __shfl_xor(sd0, 1);  sd1 += __shfl_xor(sd1, 1);

    if (sub != 0 || gn >= N_NODES) return;
    float o0 = (sn0 + ai.z * sd0) / (sd0 + 1e-16f);
    float o1 = (sn1 + ai.w * sd1) / (sd1 + 1e-16f);
    out[gn] = make_float2(o0, o1);
}

extern "C" void kernel_launch(void* const* d_in, const int* in_sizes, int n_in,
                              void* d_out, int out_size, void* d_ws, size_t ws_size,
                              hipStream_t stream) {
    const float* x    = (const float*)d_in[0];
    const int*   idx  = (const int*)d_in[1];   // (2, E) flat: [0..E)=i, [E..2E)=j
    const float* Wlin = (const float*)d_in[2];
    const float* Wsrc = (const float*)d_in[3];
    const float* Wdst = (const float*)d_in[4];
    const float* Wpos = (const float*)d_in[5];
    const float* bpos = (const float*)d_in[6];
    float* out = (float*)d_out;

    char* ws = (char*)d_ws;
    size_t off = 0;
    float4* tabJ  = (float4*)(ws + off); off += (size_t)N_NODES * 16;            //  3.2 MB
    float4* tabI4 = (float4*)(ws + off); off += (size_t)N_NODES * 16;            //  3.2 MB
    unsigned* packed = (unsigned*)(ws + off); off += (size_t)NCOARSE * CAP * 4;  // 27.2 MB
    unsigned* gcnt   = (unsigned*)(ws + off); off += (size_t)NCOARSE * 4;        // ~33.6 MB total (ws=256MiB)

    hipMemsetAsync(gcnt, 0, (size_t)NCOARSE * sizeof(unsigned), stream);
    scatter_kernel<<<NBLK, 512, 0, stream>>>(x, Wlin, Wsrc, Wdst, Wpos, bpos,
                                             idx, gcnt, packed, tabJ, tabI4);
    bucket_agg_kernel<<<NCOARSE, 1024, 0, stream>>>(packed, gcnt,
                                                    tabJ, tabI4, (float2*)out);
}